// Round 1
// 1618.537 us; speedup vs baseline: 1.0493x; 1.0493x over previous
//
#include <hip/hip_runtime.h>
#include <cstdint>
#include <cstddef>

// ---------------------------------------------------------------------------
// WindowAttention (Swin-style) on MI355X / gfx950.
//   B=2048 windows, N=64 tokens, DIM=512, HEADS=16, HEAD_DIM=32, NW=64 masks.
// Pipeline:
//   prep:  q -> bf16 ; [q_w*SCALE ; kv_w] -> bf16 B^T (1536x512); proj_w -> bf16;
//          bias_table[rel_index] -> biasF[16][64][64]; fused bias vector bc.
//   gemm1: QKV[m][1536] = q @ Wc^T + bc      (bf16 MFMA, 256^2 8-phase tile)
//   attn:  per (b,h) wave: S=QK^T (MFMA) + bias + mask, softmax (in-regs),
//          attn -> d_out fp32, P@V (MFMA) -> xh bf16
//   gemm3: x = xh @ proj_w^T + proj_b -> d_out fp32
// Workspace: 539,236,352 bytes (xh aliases the q-bf16 buffer; safe: sequential).
//
// R1: gemm_bt rewritten from the m97 128^2/2-barrier structure (drains vmcnt(0)
//     every K-step; ~900 TF ceiling) to the 256^2 8-phase counted-vmcnt
//     schedule (learn_hip m201 class, ~1.5 PF):
//       - 512 thr = 8 waves (2M x 4N), per-wave C = 128x64 (8x4 frags)
//       - LDS 128 KiB: 2 buffers x (A 256x64 + B 256x64) bf16
//       - per phase: {ds_read frag subtile; stage 1 half-tile; barrier;
//         lgkmcnt(0); setprio(1); 16 MFMA; setprio(0); barrier}
//       - vmcnt(6) only at phases 4 and 8 (3 half-tiles in flight);
//         final iteration phase 4 uses vmcnt(0) (its tail stages are skipped)
//     Stagger invariant: each half-tile staged one phase AFTER its region's
//     last read (overwrite-safe via that phase's barriers), and >=3 phases
//     before its first read (landing guaranteed by the phase-4/8 waits).
// ---------------------------------------------------------------------------

typedef __bf16 bf16x8 __attribute__((ext_vector_type(8)));
typedef float  f32x4  __attribute__((ext_vector_type(4)));

#define MFMA16(a, b, c) __builtin_amdgcn_mfma_f32_16x16x32_bf16(a, b, c, 0, 0, 0)

__device__ __forceinline__ unsigned short f2bf(float f) {
  unsigned u = __float_as_uint(f);
  u += 0x7fffu + ((u >> 16) & 1u);   // round-to-nearest-even
  return (unsigned short)(u >> 16);
}

// async global->LDS, 16B per lane (global_load_lds_dwordx4)
__device__ __forceinline__ void gl2lds16(const void* g, void* l) {
  __builtin_amdgcn_global_load_lds(
      (const __attribute__((address_space(1))) void*)g,
      (__attribute__((address_space(3))) void*)l, 16, 0, 0);
}

// ---------------------------------------------------------------------------
// prep kernels (unchanged)
// ---------------------------------------------------------------------------

__global__ __launch_bounds__(256) void cast_q_k(const float* __restrict__ src,
                                                unsigned short* __restrict__ dst) {
  long idx = (long)blockIdx.x * 256 + threadIdx.x;  // chunk of 8
  const float4* p = (const float4*)(src + idx * 8);
  float4 a = p[0], b = p[1];
  ushort4 r0 = make_ushort4(f2bf(a.x), f2bf(a.y), f2bf(a.z), f2bf(a.w));
  ushort4 r1 = make_ushort4(f2bf(b.x), f2bf(b.y), f2bf(b.z), f2bf(b.w));
  ushort4* o = (ushort4*)(dst + idx * 8);
  o[0] = r0; o[1] = r1;
}

__global__ __launch_bounds__(256) void pack_w_k(const float* __restrict__ qw,
                                                const float* __restrict__ kvw,
                                                const float* __restrict__ pwsrc,
                                                unsigned short* __restrict__ Wc,
                                                unsigned short* __restrict__ pw,
                                                float scale) {
  int idx = blockIdx.x * 256 + threadIdx.x;
  const float* src;
  unsigned short* dst;
  float s = 1.0f;
  if (idx < 98304) {
    long e = (long)idx * 8;
    int row = (int)(e >> 9);
    int k = (int)(e & 511);
    if (row < 512) { src = qw + (long)row * 512 + k; s = scale; }
    else           { src = kvw + (long)(row - 512) * 512 + k; }
    dst = Wc + e;
  } else {
    long e = (long)(idx - 98304) * 8;
    src = pwsrc + e;
    dst = pw + e;
  }
  float4 a = ((const float4*)src)[0];
  float4 b = ((const float4*)src)[1];
  ushort4 r0 = make_ushort4(f2bf(a.x * s), f2bf(a.y * s), f2bf(a.z * s), f2bf(a.w * s));
  ushort4 r1 = make_ushort4(f2bf(b.x * s), f2bf(b.y * s), f2bf(b.z * s), f2bf(b.w * s));
  ((ushort4*)dst)[0] = r0;
  ((ushort4*)dst)[1] = r1;
}

__global__ __launch_bounds__(256) void prep_misc_k(const float* __restrict__ btab,
                                                   const int* __restrict__ rel,
                                                   const float* __restrict__ qb,
                                                   const float* __restrict__ kvb,
                                                   float* __restrict__ biasF,
                                                   float* __restrict__ bc,
                                                   float scale) {
  int idx = blockIdx.x * 256 + threadIdx.x;
  if (idx < 65536) {
    int ij = idx & 4095;
    int h = idx >> 12;
    biasF[idx] = btab[rel[ij] * 16 + h];
  } else {
    int i = idx - 65536;
    bc[i] = (i < 512) ? qb[i] * scale : kvb[i - 512];
  }
}

// ---------------------------------------------------------------------------
// bf16 B^T GEMM, 8-phase 256^2 schedule: C[m][n] = sum_k A[m][k]*B[n][k]+bias[n]
// A: M x 512 bf16, B: N x 512 bf16, K fixed 512 (8 K-tiles of BK=64, 4 iters).
// Waves: wm in {0,1} (M), wn in {0..3} (N). Per-wave C rows:
//   m = (mi>>2)*128 + wm*64 + (mi&3)*16 + (quad*4+reg), mi = 0..7
//   n = (ni>>1)*128 + wn*32 + (ni&1)*16 + col,           ni = 0..3
// so quadrant Q(mh,nh) reads exactly the contiguous A/B half-tiles.
// LDS chunk swizzle: chunk cl of row r holds global 16B-chunk cl^(r&7);
// frag read chunk = (ks*4+quad)^(col&7)  (r&7 == col&7 for all frag rows).
// ---------------------------------------------------------------------------

#define BAR()   asm volatile("s_barrier" ::: "memory")
#define LGKM0() asm volatile("s_waitcnt lgkmcnt(0)" ::: "memory")
#define VMW(n)  asm volatile("s_waitcnt vmcnt(" #n ")" ::: "memory")

template <bool BF16OUT>
__global__ __launch_bounds__(512, 2) void gemm_bt(const unsigned short* __restrict__ A,
                                                  const unsigned short* __restrict__ B,
                                                  const float* __restrict__ bias,
                                                  void* __restrict__ Cp, int N) {
  __shared__ unsigned short Ls[2][2][256 * 64];   // [buf][A/B][row*64+e] = 128 KiB
  const int t = threadIdx.x;
  const int lane = t & 63;
  const int wave = t >> 6;            // 0..7
  const int wm = wave >> 2;           // 0..1
  const int wn = wave & 3;            // 0..3
  const int quad = lane >> 4, col = lane & 15;
  const long m0 = (long)blockIdx.x * 256;
  const long n0 = (long)blockIdx.y * 256;

  // staging: per half-tile (128 rows x 64 cols) 1024 16B-chunks, 2/thread.
  // idx = i*512+t : row=idx>>3, cl=idx&7, global chunk cg = cl^(row&7).
  int sL[2];
  long gA[2], gB[2];
#pragma unroll
  for (int i = 0; i < 2; ++i) {
    int idx = i * 512 + t;
    int row = idx >> 3, cl = idx & 7;
    int cg = cl ^ (row & 7);
    sL[i] = idx * 8;                       // element offset within a half
    gA[i] = (m0 + row) * 512 + cg * 8;
    gB[i] = (n0 + row) * 512 + cg * 8;
  }

#define ST_A(buf, h, kt) { \
  gl2lds16(A + gA[0] + (long)(h) * 65536 + (long)(kt) * 64, &Ls[buf][0][(h) * 8192 + sL[0]]); \
  gl2lds16(A + gA[1] + (long)(h) * 65536 + (long)(kt) * 64, &Ls[buf][0][(h) * 8192 + sL[1]]); }
#define ST_B(buf, h, kt) { \
  gl2lds16(B + gB[0] + (long)(h) * 65536 + (long)(kt) * 64, &Ls[buf][1][(h) * 8192 + sL[0]]); \
  gl2lds16(B + gB[1] + (long)(h) * 65536 + (long)(kt) * 64, &Ls[buf][1][(h) * 8192 + sL[1]]); }

  // fragment row bases (elements) and k-chunk offsets
  const int cks0 = (quad ^ (col & 7)) * 8;
  const int cks1 = ((4 + quad) ^ (col & 7)) * 8;
  int rAoff[2][4], rBoff[2][2];
#pragma unroll
  for (int m4 = 0; m4 < 4; ++m4) {
    int rr = wm * 64 + m4 * 16 + col;
    rAoff[0][m4] = rr * 64;
    rAoff[1][m4] = (rr + 128) * 64;
  }
#pragma unroll
  for (int n2 = 0; n2 < 2; ++n2) {
    int rr = wn * 32 + n2 * 16 + col;
    rBoff[0][n2] = rr * 64;
    rBoff[1][n2] = (rr + 128) * 64;
  }

  bf16x8 a[4][2], b0[2][2], b1[2][2];
  f32x4 acc[8][4];
#pragma unroll
  for (int i = 0; i < 8; ++i)
#pragma unroll
    for (int j = 0; j < 4; ++j) acc[i][j] = (f32x4){0.f, 0.f, 0.f, 0.f};

#define RDA(buf, mh) { _Pragma("unroll") for (int m4 = 0; m4 < 4; ++m4) { \
    a[m4][0] = *(const bf16x8*)&Ls[buf][0][rAoff[mh][m4] + cks0]; \
    a[m4][1] = *(const bf16x8*)&Ls[buf][0][rAoff[mh][m4] + cks1]; } }
#define RDB(buf, nh, breg) { _Pragma("unroll") for (int n2 = 0; n2 < 2; ++n2) { \
    breg[n2][0] = *(const bf16x8*)&Ls[buf][1][rBoff[nh][n2] + cks0]; \
    breg[n2][1] = *(const bf16x8*)&Ls[buf][1][rBoff[nh][n2] + cks1]; } }
#define MM(mh, nh, breg) { __builtin_amdgcn_s_setprio(1); \
  _Pragma("unroll") for (int m4 = 0; m4 < 4; ++m4) \
  _Pragma("unroll") for (int n2 = 0; n2 < 2; ++n2) { \
    acc[(mh) * 4 + m4][(nh) * 2 + n2] = \
        MFMA16(a[m4][0], breg[n2][0], acc[(mh) * 4 + m4][(nh) * 2 + n2]); \
    acc[(mh) * 4 + m4][(nh) * 2 + n2] = \
        MFMA16(a[m4][1], breg[n2][1], acc[(mh) * 4 + m4][(nh) * 2 + n2]); } \
  __builtin_amdgcn_s_setprio(0); }

  // 8 phases per iteration; tiles 2it (buf0) and 2it+1 (buf1).
  // Stage map (steady state): p1: buf1.Ahi(t+1) | p2: buf0.Alo(t+2) |
  //   p3: buf0.Blo(t+2) | p4: buf0.Bhi(t+2) +vmcnt(6) | p5: buf0.Ahi(t+2) |
  //   p6: buf1.Alo(t+3) | p7: buf1.Blo(t+3) | p8: buf1.Bhi(t+3) +vmcnt(6)
#define ITER(it, LAST) { \
  const int kt1 = 2 * (it) + 1; \
  /* p1 */ RDA(0, 0); RDB(0, 0, b0); ST_A(1, 1, kt1); \
           BAR(); LGKM0(); MM(0, 0, b0); BAR(); \
  /* p2 */ RDB(0, 1, b1); if (!(LAST)) { ST_A(0, 0, kt1 + 1); } \
           BAR(); LGKM0(); MM(0, 1, b1); BAR(); \
  /* p3 */ RDA(0, 1); if (!(LAST)) { ST_B(0, 0, kt1 + 1); } \
           BAR(); LGKM0(); MM(1, 1, b1); BAR(); \
  /* p4 */ if (!(LAST)) { ST_B(0, 1, kt1 + 1); VMW(6); } else { VMW(0); } \
           BAR(); LGKM0(); MM(1, 0, b0); BAR(); \
  /* p5 */ RDA(1, 0); RDB(1, 0, b0); if (!(LAST)) { ST_A(0, 1, kt1 + 1); } \
           BAR(); LGKM0(); MM(0, 0, b0); BAR(); \
  /* p6 */ RDB(1, 1, b1); if (!(LAST)) { ST_A(1, 0, kt1 + 2); } \
           BAR(); LGKM0(); MM(0, 1, b1); BAR(); \
  /* p7 */ RDA(1, 1); if (!(LAST)) { ST_B(1, 0, kt1 + 2); } \
           BAR(); LGKM0(); MM(1, 1, b1); BAR(); \
  /* p8 */ if (!(LAST)) { ST_B(1, 1, kt1 + 2); VMW(6); } \
           BAR(); LGKM0(); MM(1, 0, b0); BAR(); \
}

  // prologue: tile0 fully + tile1 {Alo,Blo,Bhi}; vmcnt(6) -> tile0 landed
  ST_A(0, 0, 0); ST_B(0, 0, 0); ST_B(0, 1, 0); ST_A(0, 1, 0);
  ST_A(1, 0, 1); ST_B(1, 0, 1); ST_B(1, 1, 1);
  VMW(6); BAR();

  for (int it = 0; it < 3; ++it) { ITER(it, 0); }
  ITER(3, 1);

  // epilogue: C/D layout col=lane&15, row=quad*4+reg
#pragma unroll
  for (int ni = 0; ni < 4; ++ni) {
    long n = n0 + (ni >> 1) * 128 + wn * 32 + (ni & 1) * 16 + col;
    float bv = bias[n];
#pragma unroll
    for (int mi = 0; mi < 8; ++mi) {
      long mb = m0 + (mi >> 2) * 128 + wm * 64 + (mi & 3) * 16 + quad * 4;
#pragma unroll
      for (int r = 0; r < 4; ++r) {
        float v = acc[mi][ni][r] + bv;
        long off = (mb + r) * N + n;
        if (BF16OUT) ((unsigned short*)Cp)[off] = f2bf(v);
        else         ((float*)Cp)[off] = v;
      }
    }
  }
#undef ST_A
#undef ST_B
#undef RDA
#undef RDB
#undef MM
#undef ITER
}

// ---------------------------------------------------------------------------
// attention: one 64-lane wave per (b,h). (unchanged this round)
// QKV layout: [m=b*64+n][o], o: 0..511 q*SCALE, 512..1023 k, 1024..1535 v,
// with head columns h*32+d inside each group.
// ---------------------------------------------------------------------------
__global__ __launch_bounds__(64) void attn_k(const unsigned short* __restrict__ QKV,
                                             const float* __restrict__ mask,
                                             const float* __restrict__ biasF,
                                             float* __restrict__ attn_out,
                                             unsigned short* __restrict__ xh) {
  __shared__ unsigned short Plds[64 * 72];  // P bf16, stride 72 (16B-aligned rows)
  __shared__ unsigned short Vt[32 * 72];    // V^T bf16 [d][j]
  const int bh = blockIdx.x;
  const int b = bh >> 4, h = bh & 15;
  const int lane = threadIdx.x;
  const int quad = lane >> 4, col = lane & 15;
  const unsigned short* base = QKV + (long)b * 64 * 1536 + h * 32;

  // transpose V (64x32) into Vt[d][j]; lane owns row j=lane
  {
    const unsigned short* vrow = base + 1024 + (long)lane * 1536;
#pragma unroll
    for (int c = 0; c < 4; ++c) {
      uint4 v = *(const uint4*)(vrow + c * 8);
      unsigned short* p = &Vt[(c * 8) * 72 + lane];
      p[0 * 72] = (unsigned short)(v.x);
      p[1 * 72] = (unsigned short)(v.x >> 16);
      p[2 * 72] = (unsigned short)(v.y);
      p[3 * 72] = (unsigned short)(v.y >> 16);
      p[4 * 72] = (unsigned short)(v.z);
      p[5 * 72] = (unsigned short)(v.z >> 16);
      p[6 * 72] = (unsigned short)(v.w);
      p[7 * 72] = (unsigned short)(v.w >> 16);
    }
  }

  // S = (Q*SCALE) K^T via MFMA; A/B frags straight from global (16B/lane)
  bf16x8 qf[4], kf[4];
#pragma unroll
  for (int mt = 0; mt < 4; ++mt)
    qf[mt] = *(const bf16x8*)(base + (long)(mt * 16 + col) * 1536 + quad * 8);
#pragma unroll
  for (int nt = 0; nt < 4; ++nt)
    kf[nt] = *(const bf16x8*)(base + 512 + (long)(nt * 16 + col) * 1536 + quad * 8);

  const f32x4 z = (f32x4){0.f, 0.f, 0.f, 0.f};
  f32x4 s[4][4];
#pragma unroll
  for (int mt = 0; mt < 4; ++mt)
#pragma unroll
    for (int nt = 0; nt < 4; ++nt)
      s[mt][nt] = MFMA16(qf[mt], kf[nt], z);

  // + bias + mask
  const float* mrow = mask + (long)(b & 63) * 4096;
  const float* brow = biasF + (long)h * 4096;
#pragma unroll
  for (int mt = 0; mt < 4; ++mt)
#pragma unroll
    for (int r = 0; r < 4; ++r) {
      int i = mt * 16 + quad * 4 + r;
#pragma unroll
      for (int nt = 0; nt < 4; ++nt) {
        int j = nt * 16 + col;
        s[mt][nt][r] += mrow[i * 64 + j] + brow[i * 64 + j];
      }
    }

  // softmax per row: row lives across lane&15 (x4 nt) at fixed quad
  float inv[4][4];
#pragma unroll
  for (int mt = 0; mt < 4; ++mt)
#pragma unroll
    for (int r = 0; r < 4; ++r) {
      float m = fmaxf(fmaxf(s[mt][0][r], s[mt][1][r]), fmaxf(s[mt][2][r], s[mt][3][r]));
      m = fmaxf(m, __shfl_xor(m, 1));
      m = fmaxf(m, __shfl_xor(m, 2));
      m = fmaxf(m, __shfl_xor(m, 4));
      m = fmaxf(m, __shfl_xor(m, 8));
      float sum = 0.f;
#pragma unroll
      for (int nt = 0; nt < 4; ++nt) {
        float p = __expf(s[mt][nt][r] - m);
        s[mt][nt][r] = p;
        sum += p;
      }
      sum += __shfl_xor(sum, 1);
      sum += __shfl_xor(sum, 2);
      sum += __shfl_xor(sum, 4);
      sum += __shfl_xor(sum, 8);
      inv[mt][r] = 1.0f / sum;
    }

  // write attn (fp32, required output) + P bf16 to LDS
  float* aout = attn_out + (long)bh * 4096;
#pragma unroll
  for (int mt = 0; mt < 4; ++mt)
#pragma unroll
    for (int r = 0; r < 4; ++r) {
      int i = mt * 16 + quad * 4 + r;
      float iv = inv[mt][r];
#pragma unroll
      for (int nt = 0; nt < 4; ++nt) {
        int j = nt * 16 + col;
        float p = s[mt][nt][r] * iv;
        aout[i * 64 + j] = p;
        Plds[i * 72 + j] = f2bf(p);
      }
    }
  __syncthreads();

  // O = P V  (A = P rows, B = Vt rows)
  f32x4 o[4][2];
#pragma unroll
  for (int mt = 0; mt < 4; ++mt)
#pragma unroll
    for (int n2 = 0; n2 < 2; ++n2) o[mt][n2] = z;
#pragma unroll
  for (int ks = 0; ks < 2; ++ks) {
    bf16x8 pa[4], vb[2];
#pragma unroll
    for (int mt = 0; mt < 4; ++mt)
      pa[mt] = *(const bf16x8*)&Plds[(mt * 16 + col) * 72 + ks * 32 + quad * 8];
#pragma unroll
    for (int n2 = 0; n2 < 2; ++n2)
      vb[n2] = *(const bf16x8*)&Vt[(n2 * 16 + col) * 72 + ks * 32 + quad * 8];
#pragma unroll
    for (int mt = 0; mt < 4; ++mt)
#pragma unroll
      for (int n2 = 0; n2 < 2; ++n2)
        o[mt][n2] = MFMA16(pa[mt], vb[n2], o[mt][n2]);
  }

  // xh[m=b*64+i][h*32+d] bf16
  unsigned short* xrow = xh + (long)b * 64 * 512 + h * 32;
#pragma unroll
  for (int mt = 0; mt < 4; ++mt)
#pragma unroll
    for (int n2 = 0; n2 < 2; ++n2)
#pragma unroll
      for (int r = 0; r < 4; ++r) {
        int i = mt * 16 + quad * 4 + r;
        int d = n2 * 16 + col;
        xrow[(long)i * 512 + d] = f2bf(o[mt][n2][r]);
      }
}

// ---------------------------------------------------------------------------
extern "C" void kernel_launch(void* const* d_in, const int* in_sizes, int n_in,
                              void* d_out, int out_size, void* d_ws, size_t ws_size,
                              hipStream_t stream) {
  const float* q      = (const float*)d_in[0];
  const float* mask   = (const float*)d_in[1];
  const float* q_w    = (const float*)d_in[2];
  const float* q_b    = (const float*)d_in[3];
  const float* kv_w   = (const float*)d_in[4];
  const float* kv_b   = (const float*)d_in[5];
  const float* proj_w = (const float*)d_in[6];
  const float* proj_b = (const float*)d_in[7];
  const float* btab   = (const float*)d_in[8];
  const int*   rel    = (const int*)d_in[9];

  char* ws = (char*)d_ws;
  unsigned short* Aq    = (unsigned short*)ws;                       // 134,217,728 B
  unsigned short* QKV   = (unsigned short*)(ws + 134217728LL);       // 402,653,184 B
  unsigned short* Wc    = (unsigned short*)(ws + 536870912LL);       //   1,572,864 B
  float*          bc    = (float*)(ws + 538443776LL);                //       6,144 B
  unsigned short* pw    = (unsigned short*)(ws + 538449920LL);       //     524,288 B
  float*          biasF = (float*)(ws + 538974208LL);                //     262,144 B
  unsigned short* xh    = Aq;  // alias: Aq dead after gemm1, xh written after

  float* x_out = (float*)d_out;
  float* attn_out = x_out + 67108864LL;  // x: 2048*64*512, attn: 2048*16*64*64

  const float scale = 0.17677669529663687f;  // HEAD_DIM^-0.5

  cast_q_k<<<32768, 256, 0, stream>>>(q, Aq);
  pack_w_k<<<512, 256, 0, stream>>>(q_w, kv_w, proj_w, Wc, pw, scale);
  prep_misc_k<<<262, 256, 0, stream>>>(btab, rel, q_b, kv_b, biasF, bc, scale);
  gemm_bt<true><<<dim3(512, 6), 512, 0, stream>>>(Aq, Wc, bc, (void*)QKV, 1536);
  attn_k<<<32768, 64, 0, stream>>>(QKV, mask, biasF, attn_out, xh);
  gemm_bt<false><<<dim3(512, 2), 512, 0, stream>>>(xh, pw, proj_b, (void*)x_out, 512);
}

// Round 2
// 1530.440 us; speedup vs baseline: 1.1097x; 1.0576x over previous
//
#include <hip/hip_runtime.h>
#include <cstdint>
#include <cstddef>

// ---------------------------------------------------------------------------
// WindowAttention (Swin-style) on MI355X / gfx950.
//   B=2048 windows, N=64 tokens, DIM=512, HEADS=16, HEAD_DIM=32, NW=64 masks.
// Pipeline:
//   prep:  q -> bf16 ; [q_w*SCALE ; kv_w] -> bf16 B^T (1536x512); proj_w -> bf16;
//          bias_table[rel_index] -> biasF[16][64][64]; fused bias vector bc.
//   gemm1: QKV[m][1536] = q @ Wc^T + bc      (bf16 MFMA, 256^2 8-phase tile)
//   attn:  per (b, head-PAIR) block (2 waves, 1 head each): S=QK^T (MFMA)
//          + bias + mask, softmax (in-regs), attn -> d_out fp32, P@V -> xh bf16
//   gemm3: x = xh @ proj_w^T + proj_b -> d_out fp32
// Workspace: 539,236,352 bytes (xh aliases the q-bf16 buffer; safe: sequential).
//
// R1: gemm_bt = 256^2 8-phase counted-vmcnt schedule (m201 class). See ITER.
// R2: attn_k pairs heads {2g, 2g+1} into one 128-thread block. QKV rows have
//     stride 3072B; each 128B cache line covers exactly one head PAIR's 64B+64B
//     slices. Pairing makes every QKV line fetched by exactly ONE block
//     (was: two blocks on arbitrary XCDs -> ~2x HBM fetch), and the mask rows
//     (same b) are L1-shared by both waves. LDS 27.6KB/block -> 10 waves/CU.
// ---------------------------------------------------------------------------

typedef __bf16 bf16x8 __attribute__((ext_vector_type(8)));
typedef float  f32x4  __attribute__((ext_vector_type(4)));

#define MFMA16(a, b, c) __builtin_amdgcn_mfma_f32_16x16x32_bf16(a, b, c, 0, 0, 0)

__device__ __forceinline__ unsigned short f2bf(float f) {
  unsigned u = __float_as_uint(f);
  u += 0x7fffu + ((u >> 16) & 1u);   // round-to-nearest-even
  return (unsigned short)(u >> 16);
}

// async global->LDS, 16B per lane (global_load_lds_dwordx4)
__device__ __forceinline__ void gl2lds16(const void* g, void* l) {
  __builtin_amdgcn_global_load_lds(
      (const __attribute__((address_space(1))) void*)g,
      (__attribute__((address_space(3))) void*)l, 16, 0, 0);
}

// ---------------------------------------------------------------------------
// prep kernels (unchanged)
// ---------------------------------------------------------------------------

__global__ __launch_bounds__(256) void cast_q_k(const float* __restrict__ src,
                                                unsigned short* __restrict__ dst) {
  long idx = (long)blockIdx.x * 256 + threadIdx.x;  // chunk of 8
  const float4* p = (const float4*)(src + idx * 8);
  float4 a = p[0], b = p[1];
  ushort4 r0 = make_ushort4(f2bf(a.x), f2bf(a.y), f2bf(a.z), f2bf(a.w));
  ushort4 r1 = make_ushort4(f2bf(b.x), f2bf(b.y), f2bf(b.z), f2bf(b.w));
  ushort4* o = (ushort4*)(dst + idx * 8);
  o[0] = r0; o[1] = r1;
}

__global__ __launch_bounds__(256) void pack_w_k(const float* __restrict__ qw,
                                                const float* __restrict__ kvw,
                                                const float* __restrict__ pwsrc,
                                                unsigned short* __restrict__ Wc,
                                                unsigned short* __restrict__ pw,
                                                float scale) {
  int idx = blockIdx.x * 256 + threadIdx.x;
  const float* src;
  unsigned short* dst;
  float s = 1.0f;
  if (idx < 98304) {
    long e = (long)idx * 8;
    int row = (int)(e >> 9);
    int k = (int)(e & 511);
    if (row < 512) { src = qw + (long)row * 512 + k; s = scale; }
    else           { src = kvw + (long)(row - 512) * 512 + k; }
    dst = Wc + e;
  } else {
    long e = (long)(idx - 98304) * 8;
    src = pwsrc + e;
    dst = pw + e;
  }
  float4 a = ((const float4*)src)[0];
  float4 b = ((const float4*)src)[1];
  ushort4 r0 = make_ushort4(f2bf(a.x * s), f2bf(a.y * s), f2bf(a.z * s), f2bf(a.w * s));
  ushort4 r1 = make_ushort4(f2bf(b.x * s), f2bf(b.y * s), f2bf(b.z * s), f2bf(b.w * s));
  ((ushort4*)dst)[0] = r0;
  ((ushort4*)dst)[1] = r1;
}

__global__ __launch_bounds__(256) void prep_misc_k(const float* __restrict__ btab,
                                                   const int* __restrict__ rel,
                                                   const float* __restrict__ qb,
                                                   const float* __restrict__ kvb,
                                                   float* __restrict__ biasF,
                                                   float* __restrict__ bc,
                                                   float scale) {
  int idx = blockIdx.x * 256 + threadIdx.x;
  if (idx < 65536) {
    int ij = idx & 4095;
    int h = idx >> 12;
    biasF[idx] = btab[rel[ij] * 16 + h];
  } else {
    int i = idx - 65536;
    bc[i] = (i < 512) ? qb[i] * scale : kvb[i - 512];
  }
}

// ---------------------------------------------------------------------------
// bf16 B^T GEMM, 8-phase 256^2 schedule: C[m][n] = sum_k A[m][k]*B[n][k]+bias[n]
// A: M x 512 bf16, B: N x 512 bf16, K fixed 512 (8 K-tiles of BK=64, 4 iters).
// Waves: wm in {0,1} (M), wn in {0..3} (N). Per-wave C rows:
//   m = (mi>>2)*128 + wm*64 + (mi&3)*16 + (quad*4+reg), mi = 0..7
//   n = (ni>>1)*128 + wn*32 + (ni&1)*16 + col,           ni = 0..3
// so quadrant Q(mh,nh) reads exactly the contiguous A/B half-tiles.
// LDS chunk swizzle: chunk cl of row r holds global 16B-chunk cl^(r&7);
// frag read chunk = (ks*4+quad)^(col&7)  (r&7 == col&7 for all frag rows).
// ---------------------------------------------------------------------------

#define BAR()   asm volatile("s_barrier" ::: "memory")
#define LGKM0() asm volatile("s_waitcnt lgkmcnt(0)" ::: "memory")
#define VMW(n)  asm volatile("s_waitcnt vmcnt(" #n ")" ::: "memory")

template <bool BF16OUT>
__global__ __launch_bounds__(512, 2) void gemm_bt(const unsigned short* __restrict__ A,
                                                  const unsigned short* __restrict__ B,
                                                  const float* __restrict__ bias,
                                                  void* __restrict__ Cp, int N) {
  __shared__ unsigned short Ls[2][2][256 * 64];   // [buf][A/B][row*64+e] = 128 KiB
  const int t = threadIdx.x;
  const int lane = t & 63;
  const int wave = t >> 6;            // 0..7
  const int wm = wave >> 2;           // 0..1
  const int wn = wave & 3;            // 0..3
  const int quad = lane >> 4, col = lane & 15;
  const long m0 = (long)blockIdx.x * 256;
  const long n0 = (long)blockIdx.y * 256;

  // staging: per half-tile (128 rows x 64 cols) 1024 16B-chunks, 2/thread.
  // idx = i*512+t : row=idx>>3, cl=idx&7, global chunk cg = cl^(row&7).
  int sL[2];
  long gA[2], gB[2];
#pragma unroll
  for (int i = 0; i < 2; ++i) {
    int idx = i * 512 + t;
    int row = idx >> 3, cl = idx & 7;
    int cg = cl ^ (row & 7);
    sL[i] = idx * 8;                       // element offset within a half
    gA[i] = (m0 + row) * 512 + cg * 8;
    gB[i] = (n0 + row) * 512 + cg * 8;
  }

#define ST_A(buf, h, kt) { \
  gl2lds16(A + gA[0] + (long)(h) * 65536 + (long)(kt) * 64, &Ls[buf][0][(h) * 8192 + sL[0]]); \
  gl2lds16(A + gA[1] + (long)(h) * 65536 + (long)(kt) * 64, &Ls[buf][0][(h) * 8192 + sL[1]]); }
#define ST_B(buf, h, kt) { \
  gl2lds16(B + gB[0] + (long)(h) * 65536 + (long)(kt) * 64, &Ls[buf][1][(h) * 8192 + sL[0]]); \
  gl2lds16(B + gB[1] + (long)(h) * 65536 + (long)(kt) * 64, &Ls[buf][1][(h) * 8192 + sL[1]]); }

  // fragment row bases (elements) and k-chunk offsets
  const int cks0 = (quad ^ (col & 7)) * 8;
  const int cks1 = ((4 + quad) ^ (col & 7)) * 8;
  int rAoff[2][4], rBoff[2][2];
#pragma unroll
  for (int m4 = 0; m4 < 4; ++m4) {
    int rr = wm * 64 + m4 * 16 + col;
    rAoff[0][m4] = rr * 64;
    rAoff[1][m4] = (rr + 128) * 64;
  }
#pragma unroll
  for (int n2 = 0; n2 < 2; ++n2) {
    int rr = wn * 32 + n2 * 16 + col;
    rBoff[0][n2] = rr * 64;
    rBoff[1][n2] = (rr + 128) * 64;
  }

  bf16x8 a[4][2], b0[2][2], b1[2][2];
  f32x4 acc[8][4];
#pragma unroll
  for (int i = 0; i < 8; ++i)
#pragma unroll
    for (int j = 0; j < 4; ++j) acc[i][j] = (f32x4){0.f, 0.f, 0.f, 0.f};

#define RDA(buf, mh) { _Pragma("unroll") for (int m4 = 0; m4 < 4; ++m4) { \
    a[m4][0] = *(const bf16x8*)&Ls[buf][0][rAoff[mh][m4] + cks0]; \
    a[m4][1] = *(const bf16x8*)&Ls[buf][0][rAoff[mh][m4] + cks1]; } }
#define RDB(buf, nh, breg) { _Pragma("unroll") for (int n2 = 0; n2 < 2; ++n2) { \
    breg[n2][0] = *(const bf16x8*)&Ls[buf][1][rBoff[nh][n2] + cks0]; \
    breg[n2][1] = *(const bf16x8*)&Ls[buf][1][rBoff[nh][n2] + cks1]; } }
#define MM(mh, nh, breg) { __builtin_amdgcn_s_setprio(1); \
  _Pragma("unroll") for (int m4 = 0; m4 < 4; ++m4) \
  _Pragma("unroll") for (int n2 = 0; n2 < 2; ++n2) { \
    acc[(mh) * 4 + m4][(nh) * 2 + n2] = \
        MFMA16(a[m4][0], breg[n2][0], acc[(mh) * 4 + m4][(nh) * 2 + n2]); \
    acc[(mh) * 4 + m4][(nh) * 2 + n2] = \
        MFMA16(a[m4][1], breg[n2][1], acc[(mh) * 4 + m4][(nh) * 2 + n2]); } \
  __builtin_amdgcn_s_setprio(0); }

  // 8 phases per iteration; tiles 2it (buf0) and 2it+1 (buf1).
  // Stage map (steady state): p1: buf1.Ahi(t+1) | p2: buf0.Alo(t+2) |
  //   p3: buf0.Blo(t+2) | p4: buf0.Bhi(t+2) +vmcnt(6) | p5: buf0.Ahi(t+2) |
  //   p6: buf1.Alo(t+3) | p7: buf1.Blo(t+3) | p8: buf1.Bhi(t+3) +vmcnt(6)
#define ITER(it, LAST) { \
  const int kt1 = 2 * (it) + 1; \
  /* p1 */ RDA(0, 0); RDB(0, 0, b0); ST_A(1, 1, kt1); \
           BAR(); LGKM0(); MM(0, 0, b0); BAR(); \
  /* p2 */ RDB(0, 1, b1); if (!(LAST)) { ST_A(0, 0, kt1 + 1); } \
           BAR(); LGKM0(); MM(0, 1, b1); BAR(); \
  /* p3 */ RDA(0, 1); if (!(LAST)) { ST_B(0, 0, kt1 + 1); } \
           BAR(); LGKM0(); MM(1, 1, b1); BAR(); \
  /* p4 */ if (!(LAST)) { ST_B(0, 1, kt1 + 1); VMW(6); } else { VMW(0); } \
           BAR(); LGKM0(); MM(1, 0, b0); BAR(); \
  /* p5 */ RDA(1, 0); RDB(1, 0, b0); if (!(LAST)) { ST_A(0, 1, kt1 + 1); } \
           BAR(); LGKM0(); MM(0, 0, b0); BAR(); \
  /* p6 */ RDB(1, 1, b1); if (!(LAST)) { ST_A(1, 0, kt1 + 2); } \
           BAR(); LGKM0(); MM(0, 1, b1); BAR(); \
  /* p7 */ RDA(1, 1); if (!(LAST)) { ST_B(1, 0, kt1 + 2); } \
           BAR(); LGKM0(); MM(1, 1, b1); BAR(); \
  /* p8 */ if (!(LAST)) { ST_B(1, 1, kt1 + 2); VMW(6); } \
           BAR(); LGKM0(); MM(1, 0, b0); BAR(); \
}

  // prologue: tile0 fully + tile1 {Alo,Blo,Bhi}; vmcnt(6) -> tile0 landed
  ST_A(0, 0, 0); ST_B(0, 0, 0); ST_B(0, 1, 0); ST_A(0, 1, 0);
  ST_A(1, 0, 1); ST_B(1, 0, 1); ST_B(1, 1, 1);
  VMW(6); BAR();

  for (int it = 0; it < 3; ++it) { ITER(it, 0); }
  ITER(3, 1);

  // epilogue: C/D layout col=lane&15, row=quad*4+reg
#pragma unroll
  for (int ni = 0; ni < 4; ++ni) {
    long n = n0 + (ni >> 1) * 128 + wn * 32 + (ni & 1) * 16 + col;
    float bv = bias[n];
#pragma unroll
    for (int mi = 0; mi < 8; ++mi) {
      long mb = m0 + (mi >> 2) * 128 + wm * 64 + (mi & 3) * 16 + quad * 4;
#pragma unroll
      for (int r = 0; r < 4; ++r) {
        float v = acc[mi][ni][r] + bv;
        long off = (mb + r) * N + n;
        if (BF16OUT) ((unsigned short*)Cp)[off] = f2bf(v);
        else         ((float*)Cp)[off] = v;
      }
    }
  }
#undef ST_A
#undef ST_B
#undef RDA
#undef RDB
#undef MM
#undef ITER
}

// ---------------------------------------------------------------------------
// attention: one 128-thread block per (b, head-pair); wave w handles head
// h = 2*(blockIdx&7) + w. The pair's q/k/v slices (64B each) share one 128B
// cache line per row, so each QKV line is fetched by exactly one block.
// QKV layout: [m=b*64+n][o], o: 0..511 q*SCALE, 512..1023 k, 1024..1535 v,
// with head columns h*32+d inside each group.
// ---------------------------------------------------------------------------
__global__ __launch_bounds__(128) void attn_k(const unsigned short* __restrict__ QKV,
                                              const float* __restrict__ mask,
                                              const float* __restrict__ biasF,
                                              float* __restrict__ attn_out,
                                              unsigned short* __restrict__ xh) {
  __shared__ unsigned short Plds[2][64 * 72];  // per-wave P bf16 (stride 72)
  __shared__ unsigned short Vt[2][32 * 72];    // per-wave V^T bf16 [d][j]
  const int b = blockIdx.x >> 3;
  const int hg = blockIdx.x & 7;
  const int wave = threadIdx.x >> 6;
  const int h = hg * 2 + wave;
  const int lane = threadIdx.x & 63;
  const int quad = lane >> 4, col = lane & 15;
  const unsigned short* base = QKV + (long)b * 64 * 1536 + h * 32;
  unsigned short* PldsW = Plds[wave];
  unsigned short* VtW = Vt[wave];

  // transpose V (64x32) into Vt[d][j]; lane owns row j=lane
  {
    const unsigned short* vrow = base + 1024 + (long)lane * 1536;
#pragma unroll
    for (int c = 0; c < 4; ++c) {
      uint4 v = *(const uint4*)(vrow + c * 8);
      unsigned short* p = &VtW[(c * 8) * 72 + lane];
      p[0 * 72] = (unsigned short)(v.x);
      p[1 * 72] = (unsigned short)(v.x >> 16);
      p[2 * 72] = (unsigned short)(v.y);
      p[3 * 72] = (unsigned short)(v.y >> 16);
      p[4 * 72] = (unsigned short)(v.z);
      p[5 * 72] = (unsigned short)(v.z >> 16);
      p[6 * 72] = (unsigned short)(v.w);
      p[7 * 72] = (unsigned short)(v.w >> 16);
    }
  }

  // S = (Q*SCALE) K^T via MFMA; A/B frags straight from global (16B/lane)
  bf16x8 qf[4], kf[4];
#pragma unroll
  for (int mt = 0; mt < 4; ++mt)
    qf[mt] = *(const bf16x8*)(base + (long)(mt * 16 + col) * 1536 + quad * 8);
#pragma unroll
  for (int nt = 0; nt < 4; ++nt)
    kf[nt] = *(const bf16x8*)(base + 512 + (long)(nt * 16 + col) * 1536 + quad * 8);

  const f32x4 z = (f32x4){0.f, 0.f, 0.f, 0.f};
  f32x4 s[4][4];
#pragma unroll
  for (int mt = 0; mt < 4; ++mt)
#pragma unroll
    for (int nt = 0; nt < 4; ++nt)
      s[mt][nt] = MFMA16(qf[mt], kf[nt], z);

  // + bias + mask (mask rows identical for both waves -> L1-shared)
  const float* mrow = mask + (long)(b & 63) * 4096;
  const float* brow = biasF + (long)h * 4096;
#pragma unroll
  for (int mt = 0; mt < 4; ++mt)
#pragma unroll
    for (int r = 0; r < 4; ++r) {
      int i = mt * 16 + quad * 4 + r;
#pragma unroll
      for (int nt = 0; nt < 4; ++nt) {
        int j = nt * 16 + col;
        s[mt][nt][r] += mrow[i * 64 + j] + brow[i * 64 + j];
      }
    }

  // softmax per row: row lives across lane&15 (x4 nt) at fixed quad
  float inv[4][4];
#pragma unroll
  for (int mt = 0; mt < 4; ++mt)
#pragma unroll
    for (int r = 0; r < 4; ++r) {
      float m = fmaxf(fmaxf(s[mt][0][r], s[mt][1][r]), fmaxf(s[mt][2][r], s[mt][3][r]));
      m = fmaxf(m, __shfl_xor(m, 1));
      m = fmaxf(m, __shfl_xor(m, 2));
      m = fmaxf(m, __shfl_xor(m, 4));
      m = fmaxf(m, __shfl_xor(m, 8));
      float sum = 0.f;
#pragma unroll
      for (int nt = 0; nt < 4; ++nt) {
        float p = __expf(s[mt][nt][r] - m);
        s[mt][nt][r] = p;
        sum += p;
      }
      sum += __shfl_xor(sum, 1);
      sum += __shfl_xor(sum, 2);
      sum += __shfl_xor(sum, 4);
      sum += __shfl_xor(sum, 8);
      inv[mt][r] = 1.0f / sum;
    }

  // write attn (fp32, required output) + P bf16 to LDS
  float* aout = attn_out + ((long)b * 16 + h) * 4096;
#pragma unroll
  for (int mt = 0; mt < 4; ++mt)
#pragma unroll
    for (int r = 0; r < 4; ++r) {
      int i = mt * 16 + quad * 4 + r;
      float iv = inv[mt][r];
#pragma unroll
      for (int nt = 0; nt < 4; ++nt) {
        int j = nt * 16 + col;
        float p = s[mt][nt][r] * iv;
        aout[i * 64 + j] = p;
        PldsW[i * 72 + j] = f2bf(p);
      }
    }
  __syncthreads();

  // O = P V  (A = P rows, B = Vt rows)
  f32x4 o[4][2];
#pragma unroll
  for (int mt = 0; mt < 4; ++mt)
#pragma unroll
    for (int n2 = 0; n2 < 2; ++n2) o[mt][n2] = z;
#pragma unroll
  for (int ks = 0; ks < 2; ++ks) {
    bf16x8 pa[4], vb[2];
#pragma unroll
    for (int mt = 0; mt < 4; ++mt)
      pa[mt] = *(const bf16x8*)&PldsW[(mt * 16 + col) * 72 + ks * 32 + quad * 8];
#pragma unroll
    for (int n2 = 0; n2 < 2; ++n2)
      vb[n2] = *(const bf16x8*)&VtW[(n2 * 16 + col) * 72 + ks * 32 + quad * 8];
#pragma unroll
    for (int mt = 0; mt < 4; ++mt)
#pragma unroll
      for (int n2 = 0; n2 < 2; ++n2)
        o[mt][n2] = MFMA16(pa[mt], vb[n2], o[mt][n2]);
  }

  // xh[m=b*64+i][h*32+d] bf16
  unsigned short* xrow = xh + (long)b * 64 * 512 + h * 32;
#pragma unroll
  for (int mt = 0; mt < 4; ++mt)
#pragma unroll
    for (int n2 = 0; n2 < 2; ++n2)
#pragma unroll
      for (int r = 0; r < 4; ++r) {
        int i = mt * 16 + quad * 4 + r;
        int d = n2 * 16 + col;
        xrow[(long)i * 512 + d] = f2bf(o[mt][n2][r]);
      }
}

// ---------------------------------------------------------------------------
extern "C" void kernel_launch(void* const* d_in, const int* in_sizes, int n_in,
                              void* d_out, int out_size, void* d_ws, size_t ws_size,
                              hipStream_t stream) {
  const float* q      = (const float*)d_in[0];
  const float* mask   = (const float*)d_in[1];
  const float* q_w    = (const float*)d_in[2];
  const float* q_b    = (const float*)d_in[3];
  const float* kv_w   = (const float*)d_in[4];
  const float* kv_b   = (const float*)d_in[5];
  const float* proj_w = (const float*)d_in[6];
  const float* proj_b = (const float*)d_in[7];
  const float* btab   = (const float*)d_in[8];
  const int*   rel    = (const int*)d_in[9];

  char* ws = (char*)d_ws;
  unsigned short* Aq    = (unsigned short*)ws;                       // 134,217,728 B
  unsigned short* QKV   = (unsigned short*)(ws + 134217728LL);       // 402,653,184 B
  unsigned short* Wc    = (unsigned short*)(ws + 536870912LL);       //   1,572,864 B
  float*          bc    = (float*)(ws + 538443776LL);                //       6,144 B
  unsigned short* pw    = (unsigned short*)(ws + 538449920LL);       //     524,288 B
  float*          biasF = (float*)(ws + 538974208LL);                //     262,144 B
  unsigned short* xh    = Aq;  // alias: Aq dead after gemm1, xh written after

  float* x_out = (float*)d_out;
  float* attn_out = x_out + 67108864LL;  // x: 2048*64*512, attn: 2048*16*64*64

  const float scale = 0.17677669529663687f;  // HEAD_DIM^-0.5

  cast_q_k<<<32768, 256, 0, stream>>>(q, Aq);
  pack_w_k<<<512, 256, 0, stream>>>(q_w, kv_w, proj_w, Wc, pw, scale);
  prep_misc_k<<<262, 256, 0, stream>>>(btab, rel, q_b, kv_b, biasF, bc, scale);
  gemm_bt<true><<<dim3(512, 6), 512, 0, stream>>>(Aq, Wc, bc, (void*)QKV, 1536);
  attn_k<<<16384, 128, 0, stream>>>(QKV, mask, biasF, attn_out, xh);
  gemm_bt<false><<<dim3(512, 2), 512, 0, stream>>>(xh, pw, proj_b, (void*)x_out, 512);
}

// Round 3
// 1510.213 us; speedup vs baseline: 1.1246x; 1.0134x over previous
//
#include <hip/hip_runtime.h>
#include <cstdint>
#include <cstddef>

// ---------------------------------------------------------------------------
// WindowAttention (Swin-style) on MI355X / gfx950.
//   B=2048 windows, N=64 tokens, DIM=512, HEADS=16, HEAD_DIM=32, NW=64 masks.
// Pipeline:
//   prep:  q -> bf16 ; [q_w*SCALE ; kv_w] -> bf16 B^T (1536x512); proj_w -> bf16;
//          bias_table[rel_index] -> biasF[16][64][64]; fused bias vector bc.
//   gemm1: QKV[m][1536] = q @ Wc^T + bc      (bf16 MFMA, 256^2 8-phase tile)
//   attn:  per (b, head-PAIR) block (2 waves, 1 head each): S=QK^T (MFMA)
//          + bias + mask, softmax (in-regs), attn -> d_out fp32, P@V -> xh bf16
//   gemm3: x = xh @ proj_w^T + proj_b -> d_out fp32
// Workspace: 539,236,352 bytes (xh aliases the q-bf16 buffer; safe: sequential).
//
// R1: gemm_bt = 256^2 8-phase counted-vmcnt schedule (m201 class). See ITER.
// R2: attn_k pairs heads {2g,2g+1} per 128-thr block -> one fetch per 128B
//     QKV line (-88 us, matched prediction).
// R3: gemm_bt tile-order swizzle. Old mapping: the GY blocks sharing an
//     A-panel were gridDim.x=512 dispatches apart -> L2 (4MB) evicted, L3
//     partially -> A re-read from HBM up to GY times. New mapping (bijective,
//     nb%8==0 in both launches): XCD-chunked (m204) + tn-fastest, so the GY
//     A-panel sharers run adjacently on ONE XCD: A fetched from HBM once,
//     re-reads are L2 hits; B-panels (<=1.5MB) stay L2-resident per XCD.
// ---------------------------------------------------------------------------

typedef __bf16 bf16x8 __attribute__((ext_vector_type(8)));
typedef float  f32x4  __attribute__((ext_vector_type(4)));

#define MFMA16(a, b, c) __builtin_amdgcn_mfma_f32_16x16x32_bf16(a, b, c, 0, 0, 0)

__device__ __forceinline__ unsigned short f2bf(float f) {
  unsigned u = __float_as_uint(f);
  u += 0x7fffu + ((u >> 16) & 1u);   // round-to-nearest-even
  return (unsigned short)(u >> 16);
}

// async global->LDS, 16B per lane (global_load_lds_dwordx4)
__device__ __forceinline__ void gl2lds16(const void* g, void* l) {
  __builtin_amdgcn_global_load_lds(
      (const __attribute__((address_space(1))) void*)g,
      (__attribute__((address_space(3))) void*)l, 16, 0, 0);
}

// ---------------------------------------------------------------------------
// prep kernels (unchanged)
// ---------------------------------------------------------------------------

__global__ __launch_bounds__(256) void cast_q_k(const float* __restrict__ src,
                                                unsigned short* __restrict__ dst) {
  long idx = (long)blockIdx.x * 256 + threadIdx.x;  // chunk of 8
  const float4* p = (const float4*)(src + idx * 8);
  float4 a = p[0], b = p[1];
  ushort4 r0 = make_ushort4(f2bf(a.x), f2bf(a.y), f2bf(a.z), f2bf(a.w));
  ushort4 r1 = make_ushort4(f2bf(b.x), f2bf(b.y), f2bf(b.z), f2bf(b.w));
  ushort4* o = (ushort4*)(dst + idx * 8);
  o[0] = r0; o[1] = r1;
}

__global__ __launch_bounds__(256) void pack_w_k(const float* __restrict__ qw,
                                                const float* __restrict__ kvw,
                                                const float* __restrict__ pwsrc,
                                                unsigned short* __restrict__ Wc,
                                                unsigned short* __restrict__ pw,
                                                float scale) {
  int idx = blockIdx.x * 256 + threadIdx.x;
  const float* src;
  unsigned short* dst;
  float s = 1.0f;
  if (idx < 98304) {
    long e = (long)idx * 8;
    int row = (int)(e >> 9);
    int k = (int)(e & 511);
    if (row < 512) { src = qw + (long)row * 512 + k; s = scale; }
    else           { src = kvw + (long)(row - 512) * 512 + k; }
    dst = Wc + e;
  } else {
    long e = (long)(idx - 98304) * 8;
    src = pwsrc + e;
    dst = pw + e;
  }
  float4 a = ((const float4*)src)[0];
  float4 b = ((const float4*)src)[1];
  ushort4 r0 = make_ushort4(f2bf(a.x * s), f2bf(a.y * s), f2bf(a.z * s), f2bf(a.w * s));
  ushort4 r1 = make_ushort4(f2bf(b.x * s), f2bf(b.y * s), f2bf(b.z * s), f2bf(b.w * s));
  ((ushort4*)dst)[0] = r0;
  ((ushort4*)dst)[1] = r1;
}

__global__ __launch_bounds__(256) void prep_misc_k(const float* __restrict__ btab,
                                                   const int* __restrict__ rel,
                                                   const float* __restrict__ qb,
                                                   const float* __restrict__ kvb,
                                                   float* __restrict__ biasF,
                                                   float* __restrict__ bc,
                                                   float scale) {
  int idx = blockIdx.x * 256 + threadIdx.x;
  if (idx < 65536) {
    int ij = idx & 4095;
    int h = idx >> 12;
    biasF[idx] = btab[rel[ij] * 16 + h];
  } else {
    int i = idx - 65536;
    bc[i] = (i < 512) ? qb[i] * scale : kvb[i - 512];
  }
}

// ---------------------------------------------------------------------------
// bf16 B^T GEMM, 8-phase 256^2 schedule: C[m][n] = sum_k A[m][k]*B[n][k]+bias[n]
// A: M x 512 bf16, B: N x 512 bf16, K fixed 512 (8 K-tiles of BK=64, 4 iters).
// Waves: wm in {0,1} (M), wn in {0..3} (N). Per-wave C rows:
//   m = (mi>>2)*128 + wm*64 + (mi&3)*16 + (quad*4+reg), mi = 0..7
//   n = (ni>>1)*128 + wn*32 + (ni&1)*16 + col,           ni = 0..3
// so quadrant Q(mh,nh) reads exactly the contiguous A/B half-tiles.
// LDS chunk swizzle: chunk cl of row r holds global 16B-chunk cl^(r&7);
// frag read chunk = (ks*4+quad)^(col&7)  (r&7 == col&7 for all frag rows).
// R3 tile remap: Ld = dispatch-linear id (bx fastest); bijective XCD chunking
//   xcd=Ld&7, pos=Ld>>3, L2i=xcd*(nb/8)+pos; tm=L2i/GY (A-panel), tn=L2i%GY.
// ---------------------------------------------------------------------------

#define BAR()   asm volatile("s_barrier" ::: "memory")
#define LGKM0() asm volatile("s_waitcnt lgkmcnt(0)" ::: "memory")
#define VMW(n)  asm volatile("s_waitcnt vmcnt(" #n ")" ::: "memory")

template <bool BF16OUT>
__global__ __launch_bounds__(512, 2) void gemm_bt(const unsigned short* __restrict__ A,
                                                  const unsigned short* __restrict__ B,
                                                  const float* __restrict__ bias,
                                                  void* __restrict__ Cp, int N) {
  __shared__ unsigned short Ls[2][2][256 * 64];   // [buf][A/B][row*64+e] = 128 KiB
  const int t = threadIdx.x;
  const int lane = t & 63;
  const int wave = t >> 6;            // 0..7
  const int wm = wave >> 2;           // 0..1
  const int wn = wave & 3;            // 0..3
  const int quad = lane >> 4, col = lane & 15;

  // R3: bijective XCD-chunked, tn-fastest tile remap (nb % 8 == 0 here).
  const int GY = gridDim.y;                       // 6 (gemm1) or 2 (gemm3)
  const int nb = gridDim.x * GY;
  int Ld = blockIdx.y * gridDim.x + blockIdx.x;   // dispatch/temporal order
  int L2i = (Ld & 7) * (nb >> 3) + (Ld >> 3);     // chunk per XCD
  const long m0 = (long)(L2i / GY) * 256;         // A-panel: GY adjacent tiles
  const long n0 = (long)(L2i % GY) * 256;

  // staging: per half-tile (128 rows x 64 cols) 1024 16B-chunks, 2/thread.
  // idx = i*512+t : row=idx>>3, cl=idx&7, global chunk cg = cl^(row&7).
  int sL[2];
  long gA[2], gB[2];
#pragma unroll
  for (int i = 0; i < 2; ++i) {
    int idx = i * 512 + t;
    int row = idx >> 3, cl = idx & 7;
    int cg = cl ^ (row & 7);
    sL[i] = idx * 8;                       // element offset within a half
    gA[i] = (m0 + row) * 512 + cg * 8;
    gB[i] = (n0 + row) * 512 + cg * 8;
  }

#define ST_A(buf, h, kt) { \
  gl2lds16(A + gA[0] + (long)(h) * 65536 + (long)(kt) * 64, &Ls[buf][0][(h) * 8192 + sL[0]]); \
  gl2lds16(A + gA[1] + (long)(h) * 65536 + (long)(kt) * 64, &Ls[buf][0][(h) * 8192 + sL[1]]); }
#define ST_B(buf, h, kt) { \
  gl2lds16(B + gB[0] + (long)(h) * 65536 + (long)(kt) * 64, &Ls[buf][1][(h) * 8192 + sL[0]]); \
  gl2lds16(B + gB[1] + (long)(h) * 65536 + (long)(kt) * 64, &Ls[buf][1][(h) * 8192 + sL[1]]); }

  // fragment row bases (elements) and k-chunk offsets
  const int cks0 = (quad ^ (col & 7)) * 8;
  const int cks1 = ((4 + quad) ^ (col & 7)) * 8;
  int rAoff[2][4], rBoff[2][2];
#pragma unroll
  for (int m4 = 0; m4 < 4; ++m4) {
    int rr = wm * 64 + m4 * 16 + col;
    rAoff[0][m4] = rr * 64;
    rAoff[1][m4] = (rr + 128) * 64;
  }
#pragma unroll
  for (int n2 = 0; n2 < 2; ++n2) {
    int rr = wn * 32 + n2 * 16 + col;
    rBoff[0][n2] = rr * 64;
    rBoff[1][n2] = (rr + 128) * 64;
  }

  bf16x8 a[4][2], b0[2][2], b1[2][2];
  f32x4 acc[8][4];
#pragma unroll
  for (int i = 0; i < 8; ++i)
#pragma unroll
    for (int j = 0; j < 4; ++j) acc[i][j] = (f32x4){0.f, 0.f, 0.f, 0.f};

#define RDA(buf, mh) { _Pragma("unroll") for (int m4 = 0; m4 < 4; ++m4) { \
    a[m4][0] = *(const bf16x8*)&Ls[buf][0][rAoff[mh][m4] + cks0]; \
    a[m4][1] = *(const bf16x8*)&Ls[buf][0][rAoff[mh][m4] + cks1]; } }
#define RDB(buf, nh, breg) { _Pragma("unroll") for (int n2 = 0; n2 < 2; ++n2) { \
    breg[n2][0] = *(const bf16x8*)&Ls[buf][1][rBoff[nh][n2] + cks0]; \
    breg[n2][1] = *(const bf16x8*)&Ls[buf][1][rBoff[nh][n2] + cks1]; } }
#define MM(mh, nh, breg) { __builtin_amdgcn_s_setprio(1); \
  _Pragma("unroll") for (int m4 = 0; m4 < 4; ++m4) \
  _Pragma("unroll") for (int n2 = 0; n2 < 2; ++n2) { \
    acc[(mh) * 4 + m4][(nh) * 2 + n2] = \
        MFMA16(a[m4][0], breg[n2][0], acc[(mh) * 4 + m4][(nh) * 2 + n2]); \
    acc[(mh) * 4 + m4][(nh) * 2 + n2] = \
        MFMA16(a[m4][1], breg[n2][1], acc[(mh) * 4 + m4][(nh) * 2 + n2]); } \
  __builtin_amdgcn_s_setprio(0); }

  // 8 phases per iteration; tiles 2it (buf0) and 2it+1 (buf1).
  // Stage map (steady state): p1: buf1.Ahi(t+1) | p2: buf0.Alo(t+2) |
  //   p3: buf0.Blo(t+2) | p4: buf0.Bhi(t+2) +vmcnt(6) | p5: buf0.Ahi(t+2) |
  //   p6: buf1.Alo(t+3) | p7: buf1.Blo(t+3) | p8: buf1.Bhi(t+3) +vmcnt(6)
#define ITER(it, LAST) { \
  const int kt1 = 2 * (it) + 1; \
  /* p1 */ RDA(0, 0); RDB(0, 0, b0); ST_A(1, 1, kt1); \
           BAR(); LGKM0(); MM(0, 0, b0); BAR(); \
  /* p2 */ RDB(0, 1, b1); if (!(LAST)) { ST_A(0, 0, kt1 + 1); } \
           BAR(); LGKM0(); MM(0, 1, b1); BAR(); \
  /* p3 */ RDA(0, 1); if (!(LAST)) { ST_B(0, 0, kt1 + 1); } \
           BAR(); LGKM0(); MM(1, 1, b1); BAR(); \
  /* p4 */ if (!(LAST)) { ST_B(0, 1, kt1 + 1); VMW(6); } else { VMW(0); } \
           BAR(); LGKM0(); MM(1, 0, b0); BAR(); \
  /* p5 */ RDA(1, 0); RDB(1, 0, b0); if (!(LAST)) { ST_A(0, 1, kt1 + 1); } \
           BAR(); LGKM0(); MM(0, 0, b0); BAR(); \
  /* p6 */ RDB(1, 1, b1); if (!(LAST)) { ST_A(1, 0, kt1 + 2); } \
           BAR(); LGKM0(); MM(0, 1, b1); BAR(); \
  /* p7 */ RDA(1, 1); if (!(LAST)) { ST_B(1, 0, kt1 + 2); } \
           BAR(); LGKM0(); MM(1, 1, b1); BAR(); \
  /* p8 */ if (!(LAST)) { ST_B(1, 1, kt1 + 2); VMW(6); } \
           BAR(); LGKM0(); MM(1, 0, b0); BAR(); \
}

  // prologue: tile0 fully + tile1 {Alo,Blo,Bhi}; vmcnt(6) -> tile0 landed
  ST_A(0, 0, 0); ST_B(0, 0, 0); ST_B(0, 1, 0); ST_A(0, 1, 0);
  ST_A(1, 0, 1); ST_B(1, 0, 1); ST_B(1, 1, 1);
  VMW(6); BAR();

  for (int it = 0; it < 3; ++it) { ITER(it, 0); }
  ITER(3, 1);

  // epilogue: C/D layout col=lane&15, row=quad*4+reg
#pragma unroll
  for (int ni = 0; ni < 4; ++ni) {
    long n = n0 + (ni >> 1) * 128 + wn * 32 + (ni & 1) * 16 + col;
    float bv = bias[n];
#pragma unroll
    for (int mi = 0; mi < 8; ++mi) {
      long mb = m0 + (mi >> 2) * 128 + wm * 64 + (mi & 3) * 16 + quad * 4;
#pragma unroll
      for (int r = 0; r < 4; ++r) {
        float v = acc[mi][ni][r] + bv;
        long off = (mb + r) * N + n;
        if (BF16OUT) ((unsigned short*)Cp)[off] = f2bf(v);
        else         ((float*)Cp)[off] = v;
      }
    }
  }
#undef ST_A
#undef ST_B
#undef RDA
#undef RDB
#undef MM
#undef ITER
}

// ---------------------------------------------------------------------------
// attention: one 128-thread block per (b, head-pair); wave w handles head
// h = 2*(blockIdx&7) + w. The pair's q/k/v slices (64B each) share one 128B
// cache line per row, so each QKV line is fetched by exactly one block.
// QKV layout: [m=b*64+n][o], o: 0..511 q*SCALE, 512..1023 k, 1024..1535 v,
// with head columns h*32+d inside each group.
// ---------------------------------------------------------------------------
__global__ __launch_bounds__(128) void attn_k(const unsigned short* __restrict__ QKV,
                                              const float* __restrict__ mask,
                                              const float* __restrict__ biasF,
                                              float* __restrict__ attn_out,
                                              unsigned short* __restrict__ xh) {
  __shared__ unsigned short Plds[2][64 * 72];  // per-wave P bf16 (stride 72)
  __shared__ unsigned short Vt[2][32 * 72];    // per-wave V^T bf16 [d][j]
  const int b = blockIdx.x >> 3;
  const int hg = blockIdx.x & 7;
  const int wave = threadIdx.x >> 6;
  const int h = hg * 2 + wave;
  const int lane = threadIdx.x & 63;
  const int quad = lane >> 4, col = lane & 15;
  const unsigned short* base = QKV + (long)b * 64 * 1536 + h * 32;
  unsigned short* PldsW = Plds[wave];
  unsigned short* VtW = Vt[wave];

  // transpose V (64x32) into Vt[d][j]; lane owns row j=lane
  {
    const unsigned short* vrow = base + 1024 + (long)lane * 1536;
#pragma unroll
    for (int c = 0; c < 4; ++c) {
      uint4 v = *(const uint4*)(vrow + c * 8);
      unsigned short* p = &VtW[(c * 8) * 72 + lane];
      p[0 * 72] = (unsigned short)(v.x);
      p[1 * 72] = (unsigned short)(v.x >> 16);
      p[2 * 72] = (unsigned short)(v.y);
      p[3 * 72] = (unsigned short)(v.y >> 16);
      p[4 * 72] = (unsigned short)(v.z);
      p[5 * 72] = (unsigned short)(v.z >> 16);
      p[6 * 72] = (unsigned short)(v.w);
      p[7 * 72] = (unsigned short)(v.w >> 16);
    }
  }

  // S = (Q*SCALE) K^T via MFMA; A/B frags straight from global (16B/lane)
  bf16x8 qf[4], kf[4];
#pragma unroll
  for (int mt = 0; mt < 4; ++mt)
    qf[mt] = *(const bf16x8*)(base + (long)(mt * 16 + col) * 1536 + quad * 8);
#pragma unroll
  for (int nt = 0; nt < 4; ++nt)
    kf[nt] = *(const bf16x8*)(base + 512 + (long)(nt * 16 + col) * 1536 + quad * 8);

  const f32x4 z = (f32x4){0.f, 0.f, 0.f, 0.f};
  f32x4 s[4][4];
#pragma unroll
  for (int mt = 0; mt < 4; ++mt)
#pragma unroll
    for (int nt = 0; nt < 4; ++nt)
      s[mt][nt] = MFMA16(qf[mt], kf[nt], z);

  // + bias + mask (mask rows identical for both waves -> L1-shared)
  const float* mrow = mask + (long)(b & 63) * 4096;
  const float* brow = biasF + (long)h * 4096;
#pragma unroll
  for (int mt = 0; mt < 4; ++mt)
#pragma unroll
    for (int r = 0; r < 4; ++r) {
      int i = mt * 16 + quad * 4 + r;
#pragma unroll
      for (int nt = 0; nt < 4; ++nt) {
        int j = nt * 16 + col;
        s[mt][nt][r] += mrow[i * 64 + j] + brow[i * 64 + j];
      }
    }

  // softmax per row: row lives across lane&15 (x4 nt) at fixed quad
  float inv[4][4];
#pragma unroll
  for (int mt = 0; mt < 4; ++mt)
#pragma unroll
    for (int r = 0; r < 4; ++r) {
      float m = fmaxf(fmaxf(s[mt][0][r], s[mt][1][r]), fmaxf(s[mt][2][r], s[mt][3][r]));
      m = fmaxf(m, __shfl_xor(m, 1));
      m = fmaxf(m, __shfl_xor(m, 2));
      m = fmaxf(m, __shfl_xor(m, 4));
      m = fmaxf(m, __shfl_xor(m, 8));
      float sum = 0.f;
#pragma unroll
      for (int nt = 0; nt < 4; ++nt) {
        float p = __expf(s[mt][nt][r] - m);
        s[mt][nt][r] = p;
        sum += p;
      }
      sum += __shfl_xor(sum, 1);
      sum += __shfl_xor(sum, 2);
      sum += __shfl_xor(sum, 4);
      sum += __shfl_xor(sum, 8);
      inv[mt][r] = 1.0f / sum;
    }

  // write attn (fp32, required output) + P bf16 to LDS
  float* aout = attn_out + ((long)b * 16 + h) * 4096;
#pragma unroll
  for (int mt = 0; mt < 4; ++mt)
#pragma unroll
    for (int r = 0; r < 4; ++r) {
      int i = mt * 16 + quad * 4 + r;
      float iv = inv[mt][r];
#pragma unroll
      for (int nt = 0; nt < 4; ++nt) {
        int j = nt * 16 + col;
        float p = s[mt][nt][r] * iv;
        aout[i * 64 + j] = p;
        PldsW[i * 72 + j] = f2bf(p);
      }
    }
  __syncthreads();

  // O = P V  (A = P rows, B = Vt rows)
  f32x4 o[4][2];
#pragma unroll
  for (int mt = 0; mt < 4; ++mt)
#pragma unroll
    for (int n2 = 0; n2 < 2; ++n2) o[mt][n2] = z;
#pragma unroll
  for (int ks = 0; ks < 2; ++ks) {
    bf16x8 pa[4], vb[2];
#pragma unroll
    for (int mt = 0; mt < 4; ++mt)
      pa[mt] = *(const bf16x8*)&PldsW[(mt * 16 + col) * 72 + ks * 32 + quad * 8];
#pragma unroll
    for (int n2 = 0; n2 < 2; ++n2)
      vb[n2] = *(const bf16x8*)&VtW[(n2 * 16 + col) * 72 + ks * 32 + quad * 8];
#pragma unroll
    for (int mt = 0; mt < 4; ++mt)
#pragma unroll
      for (int n2 = 0; n2 < 2; ++n2)
        o[mt][n2] = MFMA16(pa[mt], vb[n2], o[mt][n2]);
  }

  // xh[m=b*64+i][h*32+d] bf16
  unsigned short* xrow = xh + (long)b * 64 * 512 + h * 32;
#pragma unroll
  for (int mt = 0; mt < 4; ++mt)
#pragma unroll
    for (int n2 = 0; n2 < 2; ++n2)
#pragma unroll
      for (int r = 0; r < 4; ++r) {
        int i = mt * 16 + quad * 4 + r;
        int d = n2 * 16 + col;
        xrow[(long)i * 512 + d] = f2bf(o[mt][n2][r]);
      }
}

// ---------------------------------------------------------------------------
extern "C" void kernel_launch(void* const* d_in, const int* in_sizes, int n_in,
                              void* d_out, int out_size, void* d_ws, size_t ws_size,
                              hipStream_t stream) {
  const float* q      = (const float*)d_in[0];
  const float* mask   = (const float*)d_in[1];
  const float* q_w    = (const float*)d_in[2];
  const float* q_b    = (const float*)d_in[3];
  const float* kv_w   = (const float*)d_in[4];
  const float* kv_b   = (const float*)d_in[5];
  const float* proj_w = (const float*)d_in[6];
  const float* proj_b = (const float*)d_in[7];
  const float* btab   = (const float*)d_in[8];
  const int*   rel    = (const int*)d_in[9];

  char* ws = (char*)d_ws;
  unsigned short* Aq    = (unsigned short*)ws;                       // 134,217,728 B
  unsigned short* QKV   = (unsigned short*)(ws + 134217728LL);       // 402,653,184 B
  unsigned short* Wc    = (unsigned short*)(ws + 536870912LL);       //   1,572,864 B
  float*          bc    = (float*)(ws + 538443776LL);                //       6,144 B
  unsigned short* pw    = (unsigned short*)(ws + 538449920LL);       //     524,288 B
  float*          biasF = (float*)(ws + 538974208LL);                //     262,144 B
  unsigned short* xh    = Aq;  // alias: Aq dead after gemm1, xh written after

  float* x_out = (float*)d_out;
  float* attn_out = x_out + 67108864LL;  // x: 2048*64*512, attn: 2048*16*64*64

  const float scale = 0.17677669529663687f;  // HEAD_DIM^-0.5

  cast_q_k<<<32768, 256, 0, stream>>>(q, Aq);
  pack_w_k<<<512, 256, 0, stream>>>(q_w, kv_w, proj_w, Wc, pw, scale);
  prep_misc_k<<<262, 256, 0, stream>>>(btab, rel, q_b, kv_b, biasF, bc, scale);
  gemm_bt<true><<<dim3(512, 6), 512, 0, stream>>>(Aq, Wc, bc, (void*)QKV, 1536);
  attn_k<<<16384, 128, 0, stream>>>(QKV, mask, biasF, attn_out, xh);
  gemm_bt<false><<<dim3(512, 2), 512, 0, stream>>>(xh, pw, proj_b, (void*)x_out, 512);
}

// Round 4
// 1476.272 us; speedup vs baseline: 1.1504x; 1.0230x over previous
//
#include <hip/hip_runtime.h>
#include <cstdint>
#include <cstddef>

// ---------------------------------------------------------------------------
// WindowAttention (Swin-style) on MI355X / gfx950.
//   B=2048 windows, N=64 tokens, DIM=512, HEADS=16, HEAD_DIM=32, NW=64 masks.
// Pipeline:
//   prep:  q -> bf16 ; [q_w*SCALE ; kv_w] -> bf16 B^T (1536x512); proj_w -> bf16;
//          bias_table[rel_index] -> biasF[16][64][64]; fused bias vector bc.
//   gemm1: QKV[m][1536] = q @ Wc^T + bc      (bf16 MFMA, 256^2 8-phase tile)
//   attn:  per (b, head-PAIR) block (2 waves, 1 head each): S=QK^T (MFMA)
//          + bias + mask, softmax (in-regs), attn -> d_out fp32, P@V -> xh bf16
//   gemm3: x = xh @ proj_w^T + proj_b -> d_out fp32
// Workspace: 539,236,352 bytes (xh aliases the q-bf16 buffer; safe: sequential).
//
// R1: gemm_bt = 256^2 8-phase counted-vmcnt schedule (m201 class). See ITER.
// R2: attn_k pairs heads {2g,2g+1} per 128-thr block -> one fetch per 128B
//     QKV line (-88 us, matched prediction).
// R3: gemm_bt bijective XCD-chunked tn-fastest tile remap (-20 us; L3 was
//     absorbing most A re-reads, swizzle upgraded them to L2 hits).
// R4: epilogue store vectorization. gemm_bt wrote C as 128 scalar stores/lane
//     (2B for bf16!) due to C/D frag layout; now each wave repacks its four
//     64x32 strips through (dead) Ls with a quad-XOR swizzle -> 32x16B
//     coalesced stores. attn_k xh likewise: 32x2B -> 4x16B via dead PldsW.
//     Bit-identical values; no traffic change; pure issue/WC win.
// ---------------------------------------------------------------------------

typedef __bf16 bf16x8 __attribute__((ext_vector_type(8)));
typedef float  f32x4  __attribute__((ext_vector_type(4)));

#define MFMA16(a, b, c) __builtin_amdgcn_mfma_f32_16x16x32_bf16(a, b, c, 0, 0, 0)

__device__ __forceinline__ unsigned short f2bf(float f) {
  unsigned u = __float_as_uint(f);
  u += 0x7fffu + ((u >> 16) & 1u);   // round-to-nearest-even
  return (unsigned short)(u >> 16);
}

// async global->LDS, 16B per lane (global_load_lds_dwordx4)
__device__ __forceinline__ void gl2lds16(const void* g, void* l) {
  __builtin_amdgcn_global_load_lds(
      (const __attribute__((address_space(1))) void*)g,
      (__attribute__((address_space(3))) void*)l, 16, 0, 0);
}

// ---------------------------------------------------------------------------
// prep kernels (unchanged)
// ---------------------------------------------------------------------------

__global__ __launch_bounds__(256) void cast_q_k(const float* __restrict__ src,
                                                unsigned short* __restrict__ dst) {
  long idx = (long)blockIdx.x * 256 + threadIdx.x;  // chunk of 8
  const float4* p = (const float4*)(src + idx * 8);
  float4 a = p[0], b = p[1];
  ushort4 r0 = make_ushort4(f2bf(a.x), f2bf(a.y), f2bf(a.z), f2bf(a.w));
  ushort4 r1 = make_ushort4(f2bf(b.x), f2bf(b.y), f2bf(b.z), f2bf(b.w));
  ushort4* o = (ushort4*)(dst + idx * 8);
  o[0] = r0; o[1] = r1;
}

__global__ __launch_bounds__(256) void pack_w_k(const float* __restrict__ qw,
                                                const float* __restrict__ kvw,
                                                const float* __restrict__ pwsrc,
                                                unsigned short* __restrict__ Wc,
                                                unsigned short* __restrict__ pw,
                                                float scale) {
  int idx = blockIdx.x * 256 + threadIdx.x;
  const float* src;
  unsigned short* dst;
  float s = 1.0f;
  if (idx < 98304) {
    long e = (long)idx * 8;
    int row = (int)(e >> 9);
    int k = (int)(e & 511);
    if (row < 512) { src = qw + (long)row * 512 + k; s = scale; }
    else           { src = kvw + (long)(row - 512) * 512 + k; }
    dst = Wc + e;
  } else {
    long e = (long)(idx - 98304) * 8;
    src = pwsrc + e;
    dst = pw + e;
  }
  float4 a = ((const float4*)src)[0];
  float4 b = ((const float4*)src)[1];
  ushort4 r0 = make_ushort4(f2bf(a.x * s), f2bf(a.y * s), f2bf(a.z * s), f2bf(a.w * s));
  ushort4 r1 = make_ushort4(f2bf(b.x * s), f2bf(b.y * s), f2bf(b.z * s), f2bf(b.w * s));
  ((ushort4*)dst)[0] = r0;
  ((ushort4*)dst)[1] = r1;
}

__global__ __launch_bounds__(256) void prep_misc_k(const float* __restrict__ btab,
                                                   const int* __restrict__ rel,
                                                   const float* __restrict__ qb,
                                                   const float* __restrict__ kvb,
                                                   float* __restrict__ biasF,
                                                   float* __restrict__ bc,
                                                   float scale) {
  int idx = blockIdx.x * 256 + threadIdx.x;
  if (idx < 65536) {
    int ij = idx & 4095;
    int h = idx >> 12;
    biasF[idx] = btab[rel[ij] * 16 + h];
  } else {
    int i = idx - 65536;
    bc[i] = (i < 512) ? qb[i] * scale : kvb[i - 512];
  }
}

// ---------------------------------------------------------------------------
// bf16 B^T GEMM, 8-phase 256^2 schedule: C[m][n] = sum_k A[m][k]*B[n][k]+bias[n]
// A: M x 512 bf16, B: N x 512 bf16, K fixed 512 (8 K-tiles of BK=64, 4 iters).
// Waves: wm in {0,1} (M), wn in {0..3} (N). Per-wave C rows:
//   m = (mi>>2)*128 + wm*64 + (mi&3)*16 + (quad*4+reg), mi = 0..7
//   n = (ni>>1)*128 + wn*32 + (ni&1)*16 + col,           ni = 0..3
// so quadrant Q(mh,nh) reads exactly the contiguous A/B half-tiles.
// LDS chunk swizzle: chunk cl of row r holds global 16B-chunk cl^(r&7);
// frag read chunk = (ks*4+quad)^(col&7)  (r&7 == col&7 for all frag rows).
// R3 tile remap: Ld = dispatch-linear id (bx fastest); bijective XCD chunking
//   xcd=Ld&7, pos=Ld>>3, L2i=xcd*(nb/8)+pos; tm=L2i/GY (A-panel), tn=L2i%GY.
// R4 epilogue: per-wave strip repack via Ls (dead after main loop); write
//   swizzle d^(quad<<3) makes both the 4B writes and b128 reads conflict-free
//   (quad is the only colliding dim; XOR spreads it across banks).
// ---------------------------------------------------------------------------

#define BAR()   asm volatile("s_barrier" ::: "memory")
#define LGKM0() asm volatile("s_waitcnt lgkmcnt(0)" ::: "memory")
#define VMW(n)  asm volatile("s_waitcnt vmcnt(" #n ")" ::: "memory")

template <bool BF16OUT>
__global__ __launch_bounds__(512, 2) void gemm_bt(const unsigned short* __restrict__ A,
                                                  const unsigned short* __restrict__ B,
                                                  const float* __restrict__ bias,
                                                  void* __restrict__ Cp, int N) {
  __shared__ unsigned short Ls[2][2][256 * 64];   // [buf][A/B][row*64+e] = 128 KiB
  const int t = threadIdx.x;
  const int lane = t & 63;
  const int wave = t >> 6;            // 0..7
  const int wm = wave >> 2;           // 0..1
  const int wn = wave & 3;            // 0..3
  const int quad = lane >> 4, col = lane & 15;

  // R3: bijective XCD-chunked, tn-fastest tile remap (nb % 8 == 0 here).
  const int GY = gridDim.y;                       // 6 (gemm1) or 2 (gemm3)
  const int nb = gridDim.x * GY;
  int Ld = blockIdx.y * gridDim.x + blockIdx.x;   // dispatch/temporal order
  int L2i = (Ld & 7) * (nb >> 3) + (Ld >> 3);     // chunk per XCD
  const long m0 = (long)(L2i / GY) * 256;         // A-panel: GY adjacent tiles
  const long n0 = (long)(L2i % GY) * 256;

  // staging: per half-tile (128 rows x 64 cols) 1024 16B-chunks, 2/thread.
  // idx = i*512+t : row=idx>>3, cl=idx&7, global chunk cg = cl^(row&7).
  int sL[2];
  long gA[2], gB[2];
#pragma unroll
  for (int i = 0; i < 2; ++i) {
    int idx = i * 512 + t;
    int row = idx >> 3, cl = idx & 7;
    int cg = cl ^ (row & 7);
    sL[i] = idx * 8;                       // element offset within a half
    gA[i] = (m0 + row) * 512 + cg * 8;
    gB[i] = (n0 + row) * 512 + cg * 8;
  }

#define ST_A(buf, h, kt) { \
  gl2lds16(A + gA[0] + (long)(h) * 65536 + (long)(kt) * 64, &Ls[buf][0][(h) * 8192 + sL[0]]); \
  gl2lds16(A + gA[1] + (long)(h) * 65536 + (long)(kt) * 64, &Ls[buf][0][(h) * 8192 + sL[1]]); }
#define ST_B(buf, h, kt) { \
  gl2lds16(B + gB[0] + (long)(h) * 65536 + (long)(kt) * 64, &Ls[buf][1][(h) * 8192 + sL[0]]); \
  gl2lds16(B + gB[1] + (long)(h) * 65536 + (long)(kt) * 64, &Ls[buf][1][(h) * 8192 + sL[1]]); }

  // fragment row bases (elements) and k-chunk offsets
  const int cks0 = (quad ^ (col & 7)) * 8;
  const int cks1 = ((4 + quad) ^ (col & 7)) * 8;
  int rAoff[2][4], rBoff[2][2];
#pragma unroll
  for (int m4 = 0; m4 < 4; ++m4) {
    int rr = wm * 64 + m4 * 16 + col;
    rAoff[0][m4] = rr * 64;
    rAoff[1][m4] = (rr + 128) * 64;
  }
#pragma unroll
  for (int n2 = 0; n2 < 2; ++n2) {
    int rr = wn * 32 + n2 * 16 + col;
    rBoff[0][n2] = rr * 64;
    rBoff[1][n2] = (rr + 128) * 64;
  }

  bf16x8 a[4][2], b0[2][2], b1[2][2];
  f32x4 acc[8][4];
#pragma unroll
  for (int i = 0; i < 8; ++i)
#pragma unroll
    for (int j = 0; j < 4; ++j) acc[i][j] = (f32x4){0.f, 0.f, 0.f, 0.f};

#define RDA(buf, mh) { _Pragma("unroll") for (int m4 = 0; m4 < 4; ++m4) { \
    a[m4][0] = *(const bf16x8*)&Ls[buf][0][rAoff[mh][m4] + cks0]; \
    a[m4][1] = *(const bf16x8*)&Ls[buf][0][rAoff[mh][m4] + cks1]; } }
#define RDB(buf, nh, breg) { _Pragma("unroll") for (int n2 = 0; n2 < 2; ++n2) { \
    breg[n2][0] = *(const bf16x8*)&Ls[buf][1][rBoff[nh][n2] + cks0]; \
    breg[n2][1] = *(const bf16x8*)&Ls[buf][1][rBoff[nh][n2] + cks1]; } }
#define MM(mh, nh, breg) { __builtin_amdgcn_s_setprio(1); \
  _Pragma("unroll") for (int m4 = 0; m4 < 4; ++m4) \
  _Pragma("unroll") for (int n2 = 0; n2 < 2; ++n2) { \
    acc[(mh) * 4 + m4][(nh) * 2 + n2] = \
        MFMA16(a[m4][0], breg[n2][0], acc[(mh) * 4 + m4][(nh) * 2 + n2]); \
    acc[(mh) * 4 + m4][(nh) * 2 + n2] = \
        MFMA16(a[m4][1], breg[n2][1], acc[(mh) * 4 + m4][(nh) * 2 + n2]); } \
  __builtin_amdgcn_s_setprio(0); }

  // 8 phases per iteration; tiles 2it (buf0) and 2it+1 (buf1).
  // Stage map (steady state): p1: buf1.Ahi(t+1) | p2: buf0.Alo(t+2) |
  //   p3: buf0.Blo(t+2) | p4: buf0.Bhi(t+2) +vmcnt(6) | p5: buf0.Ahi(t+2) |
  //   p6: buf1.Alo(t+3) | p7: buf1.Blo(t+3) | p8: buf1.Bhi(t+3) +vmcnt(6)
#define ITER(it, LAST) { \
  const int kt1 = 2 * (it) + 1; \
  /* p1 */ RDA(0, 0); RDB(0, 0, b0); ST_A(1, 1, kt1); \
           BAR(); LGKM0(); MM(0, 0, b0); BAR(); \
  /* p2 */ RDB(0, 1, b1); if (!(LAST)) { ST_A(0, 0, kt1 + 1); } \
           BAR(); LGKM0(); MM(0, 1, b1); BAR(); \
  /* p3 */ RDA(0, 1); if (!(LAST)) { ST_B(0, 0, kt1 + 1); } \
           BAR(); LGKM0(); MM(1, 1, b1); BAR(); \
  /* p4 */ if (!(LAST)) { ST_B(0, 1, kt1 + 1); VMW(6); } else { VMW(0); } \
           BAR(); LGKM0(); MM(1, 0, b0); BAR(); \
  /* p5 */ RDA(1, 0); RDB(1, 0, b0); if (!(LAST)) { ST_A(0, 1, kt1 + 1); } \
           BAR(); LGKM0(); MM(0, 0, b0); BAR(); \
  /* p6 */ RDB(1, 1, b1); if (!(LAST)) { ST_A(1, 0, kt1 + 2); } \
           BAR(); LGKM0(); MM(0, 1, b1); BAR(); \
  /* p7 */ RDA(1, 1); if (!(LAST)) { ST_B(1, 0, kt1 + 2); } \
           BAR(); LGKM0(); MM(1, 1, b1); BAR(); \
  /* p8 */ if (!(LAST)) { ST_B(1, 1, kt1 + 2); VMW(6); } \
           BAR(); LGKM0(); MM(1, 0, b0); BAR(); \
}

  // prologue: tile0 fully + tile1 {Alo,Blo,Bhi}; vmcnt(6) -> tile0 landed
  ST_A(0, 0, 0); ST_B(0, 0, 0); ST_B(0, 1, 0); ST_A(0, 1, 0);
  ST_A(1, 0, 1); ST_B(1, 0, 1); ST_B(1, 1, 1);
  VMW(6); BAR();

  for (int it = 0; it < 3; ++it) { ITER(it, 0); }
  ITER(3, 1);

  // R4 epilogue: per-wave repack via Ls (all buf reads barrier-complete; each
  // wave uses a private 8KB fp32 region = first 64KB of Ls). For each of the
  // 4 strips (mh,nh: 64 rows x 32 cols): write acc+bias with d^(quad<<3)
  // swizzle (conflict-free), read back b128, store 16B/lane coalesced.
  {
    float* lsf = (float*)&Ls[0][0][0] + wave * 2048;
#pragma unroll
    for (int mh = 0; mh < 2; ++mh)
#pragma unroll
      for (int nh = 0; nh < 2; ++nh) {
        float bvv[2];
#pragma unroll
        for (int n2 = 0; n2 < 2; ++n2)
          bvv[n2] = bias[n0 + nh * 128 + wn * 32 + n2 * 16 + col];
#pragma unroll
        for (int m4 = 0; m4 < 4; ++m4)
#pragma unroll
          for (int n2 = 0; n2 < 2; ++n2)
#pragma unroll
            for (int r = 0; r < 4; ++r) {
              int row = m4 * 16 + quad * 4 + r;
              lsf[row * 32 + ((n2 * 16 + col) ^ (quad << 3))] =
                  acc[mh * 4 + m4][nh * 2 + n2][r] + bvv[n2];
            }
        asm volatile("" ::: "memory");  // order strip write<->read (same wave)
        long mbase = m0 + mh * 128 + wm * 64;
        long nbase = n0 + nh * 128 + wn * 32;
#pragma unroll
        for (int op = 0; op < 8; ++op) {
          int rowr = op * 8 + (lane >> 3);
          int xr = ((rowr >> 2) & 3) << 3;
          f32x4 vv = *(const f32x4*)&lsf[rowr * 32 + (((lane & 7) * 4) ^ xr)];
          long off = (mbase + rowr) * N + nbase + (lane & 7) * 4;
          if (BF16OUT) {
            ushort4 s4 = make_ushort4(f2bf(vv[0]), f2bf(vv[1]), f2bf(vv[2]), f2bf(vv[3]));
            *(ushort4*)((unsigned short*)Cp + off) = s4;
          } else {
            *(f32x4*)((float*)Cp + off) = vv;
          }
        }
        asm volatile("" ::: "memory");  // order reads before next strip's writes
      }
  }
#undef ST_A
#undef ST_B
#undef RDA
#undef RDB
#undef MM
#undef ITER
}

// ---------------------------------------------------------------------------
// attention: one 128-thread block per (b, head-pair); wave w handles head
// h = 2*(blockIdx&7) + w. The pair's q/k/v slices (64B each) share one 128B
// cache line per row, so each QKV line is fetched by exactly one block.
// QKV layout: [m=b*64+n][o], o: 0..511 q*SCALE, 512..1023 k, 1024..1535 v,
// with head columns h*32+d inside each group.
// ---------------------------------------------------------------------------
__global__ __launch_bounds__(128) void attn_k(const unsigned short* __restrict__ QKV,
                                              const float* __restrict__ mask,
                                              const float* __restrict__ biasF,
                                              float* __restrict__ attn_out,
                                              unsigned short* __restrict__ xh) {
  __shared__ unsigned short Plds[2][64 * 72];  // per-wave P bf16 (stride 72)
  __shared__ unsigned short Vt[2][32 * 72];    // per-wave V^T bf16 [d][j]
  const int b = blockIdx.x >> 3;
  const int hg = blockIdx.x & 7;
  const int wave = threadIdx.x >> 6;
  const int h = hg * 2 + wave;
  const int lane = threadIdx.x & 63;
  const int quad = lane >> 4, col = lane & 15;
  const unsigned short* base = QKV + (long)b * 64 * 1536 + h * 32;
  unsigned short* PldsW = Plds[wave];
  unsigned short* VtW = Vt[wave];

  // transpose V (64x32) into Vt[d][j]; lane owns row j=lane
  {
    const unsigned short* vrow = base + 1024 + (long)lane * 1536;
#pragma unroll
    for (int c = 0; c < 4; ++c) {
      uint4 v = *(const uint4*)(vrow + c * 8);
      unsigned short* p = &VtW[(c * 8) * 72 + lane];
      p[0 * 72] = (unsigned short)(v.x);
      p[1 * 72] = (unsigned short)(v.x >> 16);
      p[2 * 72] = (unsigned short)(v.y);
      p[3 * 72] = (unsigned short)(v.y >> 16);
      p[4 * 72] = (unsigned short)(v.z);
      p[5 * 72] = (unsigned short)(v.z >> 16);
      p[6 * 72] = (unsigned short)(v.w);
      p[7 * 72] = (unsigned short)(v.w >> 16);
    }
  }

  // S = (Q*SCALE) K^T via MFMA; A/B frags straight from global (16B/lane)
  bf16x8 qf[4], kf[4];
#pragma unroll
  for (int mt = 0; mt < 4; ++mt)
    qf[mt] = *(const bf16x8*)(base + (long)(mt * 16 + col) * 1536 + quad * 8);
#pragma unroll
  for (int nt = 0; nt < 4; ++nt)
    kf[nt] = *(const bf16x8*)(base + 512 + (long)(nt * 16 + col) * 1536 + quad * 8);

  const f32x4 z = (f32x4){0.f, 0.f, 0.f, 0.f};
  f32x4 s[4][4];
#pragma unroll
  for (int mt = 0; mt < 4; ++mt)
#pragma unroll
    for (int nt = 0; nt < 4; ++nt)
      s[mt][nt] = MFMA16(qf[mt], kf[nt], z);

  // + bias + mask (mask rows identical for both waves -> L1-shared)
  const float* mrow = mask + (long)(b & 63) * 4096;
  const float* brow = biasF + (long)h * 4096;
#pragma unroll
  for (int mt = 0; mt < 4; ++mt)
#pragma unroll
    for (int r = 0; r < 4; ++r) {
      int i = mt * 16 + quad * 4 + r;
#pragma unroll
      for (int nt = 0; nt < 4; ++nt) {
        int j = nt * 16 + col;
        s[mt][nt][r] += mrow[i * 64 + j] + brow[i * 64 + j];
      }
    }

  // softmax per row: row lives across lane&15 (x4 nt) at fixed quad
  float inv[4][4];
#pragma unroll
  for (int mt = 0; mt < 4; ++mt)
#pragma unroll
    for (int r = 0; r < 4; ++r) {
      float m = fmaxf(fmaxf(s[mt][0][r], s[mt][1][r]), fmaxf(s[mt][2][r], s[mt][3][r]));
      m = fmaxf(m, __shfl_xor(m, 1));
      m = fmaxf(m, __shfl_xor(m, 2));
      m = fmaxf(m, __shfl_xor(m, 4));
      m = fmaxf(m, __shfl_xor(m, 8));
      float sum = 0.f;
#pragma unroll
      for (int nt = 0; nt < 4; ++nt) {
        float p = __expf(s[mt][nt][r] - m);
        s[mt][nt][r] = p;
        sum += p;
      }
      sum += __shfl_xor(sum, 1);
      sum += __shfl_xor(sum, 2);
      sum += __shfl_xor(sum, 4);
      sum += __shfl_xor(sum, 8);
      inv[mt][r] = 1.0f / sum;
    }

  // write attn (fp32, required output) + P bf16 to LDS
  float* aout = attn_out + ((long)b * 16 + h) * 4096;
#pragma unroll
  for (int mt = 0; mt < 4; ++mt)
#pragma unroll
    for (int r = 0; r < 4; ++r) {
      int i = mt * 16 + quad * 4 + r;
      float iv = inv[mt][r];
#pragma unroll
      for (int nt = 0; nt < 4; ++nt) {
        int j = nt * 16 + col;
        float p = s[mt][nt][r] * iv;
        aout[i * 64 + j] = p;
        PldsW[i * 72 + j] = f2bf(p);
      }
    }
  __syncthreads();

  // O = P V  (A = P rows, B = Vt rows)
  f32x4 o[4][2];
#pragma unroll
  for (int mt = 0; mt < 4; ++mt)
#pragma unroll
    for (int n2 = 0; n2 < 2; ++n2) o[mt][n2] = z;
#pragma unroll
  for (int ks = 0; ks < 2; ++ks) {
    bf16x8 pa[4], vb[2];
#pragma unroll
    for (int mt = 0; mt < 4; ++mt)
      pa[mt] = *(const bf16x8*)&PldsW[(mt * 16 + col) * 72 + ks * 32 + quad * 8];
#pragma unroll
    for (int n2 = 0; n2 < 2; ++n2)
      vb[n2] = *(const bf16x8*)&VtW[(n2 * 16 + col) * 72 + ks * 32 + quad * 8];
#pragma unroll
    for (int mt = 0; mt < 4; ++mt)
#pragma unroll
      for (int n2 = 0; n2 < 2; ++n2)
        o[mt][n2] = MFMA16(pa[mt], vb[n2], o[mt][n2]);
  }

  // R4: xh via LDS repack (PldsW dead after PV; o depends on its reads, so
  // the writes below can't precede them). Layout [i][32] with d^(quad<<3)
  // swizzle -> conflict-free 2B writes + b128 reads; 4x16B stores/lane.
#pragma unroll
  for (int mt = 0; mt < 4; ++mt)
#pragma unroll
    for (int n2 = 0; n2 < 2; ++n2)
#pragma unroll
      for (int r = 0; r < 4; ++r) {
        int row = mt * 16 + quad * 4 + r;
        PldsW[row * 32 + ((n2 * 16 + col) ^ (quad << 3))] = f2bf(o[mt][n2][r]);
      }
  asm volatile("" ::: "memory");
  unsigned short* xrow = xh + (long)b * 64 * 512 + h * 32;
#pragma unroll
  for (int op = 0; op < 4; ++op) {
    int rowr = op * 16 + (lane >> 2);
    int xr = ((rowr >> 2) & 3) << 3;
    uint4 vv = *(const uint4*)&PldsW[rowr * 32 + (((lane & 3) * 8) ^ xr)];
    *(uint4*)(xrow + (long)rowr * 512 + (lane & 3) * 8) = vv;
  }
}

// ---------------------------------------------------------------------------
extern "C" void kernel_launch(void* const* d_in, const int* in_sizes, int n_in,
                              void* d_out, int out_size, void* d_ws, size_t ws_size,
                              hipStream_t stream) {
  const float* q      = (const float*)d_in[0];
  const float* mask   = (const float*)d_in[1];
  const float* q_w    = (const float*)d_in[2];
  const float* q_b    = (const float*)d_in[3];
  const float* kv_w   = (const float*)d_in[4];
  const float* kv_b   = (const float*)d_in[5];
  const float* proj_w = (const float*)d_in[6];
  const float* proj_b = (const float*)d_in[7];
  const float* btab   = (const float*)d_in[8];
  const int*   rel    = (const int*)d_in[9];

  char* ws = (char*)d_ws;
  unsigned short* Aq    = (unsigned short*)ws;                       // 134,217,728 B
  unsigned short* QKV   = (unsigned short*)(ws + 134217728LL);       // 402,653,184 B
  unsigned short* Wc    = (unsigned short*)(ws + 536870912LL);       //   1,572,864 B
  float*          bc    = (float*)(ws + 538443776LL);                //       6,144 B
  unsigned short* pw    = (unsigned short*)(ws + 538449920LL);       //     524,288 B
  float*          biasF = (float*)(ws + 538974208LL);                //     262,144 B
  unsigned short* xh    = Aq;  // alias: Aq dead after gemm1, xh written after

  float* x_out = (float*)d_out;
  float* attn_out = x_out + 67108864LL;  // x: 2048*64*512, attn: 2048*16*64*64

  const float scale = 0.17677669529663687f;  // HEAD_DIM^-0.5

  cast_q_k<<<32768, 256, 0, stream>>>(q, Aq);
  pack_w_k<<<512, 256, 0, stream>>>(q_w, kv_w, proj_w, Wc, pw, scale);
  prep_misc_k<<<262, 256, 0, stream>>>(btab, rel, q_b, kv_b, biasF, bc, scale);
  gemm_bt<true><<<dim3(512, 6), 512, 0, stream>>>(Aq, Wc, bc, (void*)QKV, 1536);
  attn_k<<<16384, 128, 0, stream>>>(QKV, mask, biasF, attn_out, xh);
  gemm_bt<false><<<dim3(512, 2), 512, 0, stream>>>(xh, pw, proj_b, (void*)x_out, 512);
}